// Round 4
// baseline (81.321 us; speedup 1.0000x reference)
//
#include <hip/hip_runtime.h>
#include <math.h>

// ContactModel, LDS-staged coalesced-read version, round-1 numerics.
// Each 256-thread block handles output batches [B0, B0+255]. It stages the
// touched input segments (48 floats/batch) for 257 batches (rows 0..256,
// row r = batch B0-1+r clamped to [0,B-1]) into LDS with coalesced loads,
// then thread i computes batch B0+i using staged rows i+1 (own) and i (prev).
// Row clamp makes batch 0's prev == own => vel exactly 0 (reference semantics).
// LDS row stride 49 floats: (49*t+c)%32 = (17t+c)%32, 17 coprime 32 -> 2
// lanes/bank = conflict-free for wave64.
//
// Per-batch LDS columns:
//   0..6   joints floats 12..18  (bodies 4,5 positions)
//   6..12  joints floats 27..33  (bodies 9,10 positions)
//   12..30 jori   floats 36..54  (bodies 4,5 orientation)
//   30..48 jori   floats 81..99  (bodies 9,10 orientation)

__global__ __launch_bounds__(256)
void contact_kernel(const float* __restrict__ joints,
                    const float* __restrict__ jori,
                    float* __restrict__ out, const int B)
{
    __shared__ float lds[257 * 49];
    const int tid = threadIdx.x;
    const long B0 = (long)blockIdx.x * 256;

    // ---- staging (coalesced) ----
    #pragma unroll 2
    for (int idx = tid; idx < 257 * 6; idx += 256) {
        const int r = idx / 6, c = idx - r * 6;
        long br = B0 - 1 + r;
        br = br < 0 ? 0 : (br >= B ? B - 1 : br);
        lds[r * 49 + c] = joints[br * 72 + 12 + c];
    }
    #pragma unroll 2
    for (int idx = tid; idx < 257 * 6; idx += 256) {
        const int r = idx / 6, c = idx - r * 6;
        long br = B0 - 1 + r;
        br = br < 0 ? 0 : (br >= B ? B - 1 : br);
        lds[r * 49 + 6 + c] = joints[br * 72 + 27 + c];
    }
    #pragma unroll 2
    for (int idx = tid; idx < 257 * 18; idx += 256) {
        const int r = idx / 18, c = idx - r * 18;
        long br = B0 - 1 + r;
        br = br < 0 ? 0 : (br >= B ? B - 1 : br);
        lds[r * 49 + 12 + c] = jori[br * 216 + 36 + c];
    }
    #pragma unroll 2
    for (int idx = tid; idx < 257 * 18; idx += 256) {
        const int r = idx / 18, c = idx - r * 18;
        long br = B0 - 1 + r;
        br = br < 0 ? 0 : (br >= B ? B - 1 : br);
        lds[r * 49 + 30 + c] = jori[br * 216 + 81 + c];
    }
    __syncthreads();

    const long bb = B0 + tid;
    if (bb >= B) return;
    const int b = (int)bb;

    const float* own = &lds[(tid + 1) * 49];
    const float* prv = &lds[tid * 49];

    float px[12], py[12], pz[12];
    float fx[12], fy[12], fz[12];   // velocity first, then force in-place

    // ---- positions own + prev -> velocity ----
    {
        const float c_lx[12] = {0.00190115788407966f, 0.148386399942063f, 0.133001170607051f,
                                0.0662346661991635f, 0.06f, 0.045f,
                                0.00190115788407966f, 0.148386399942063f, 0.133001170607051f,
                                0.0662346661991635f, 0.06f, 0.045f};
        const float c_lz[12] = {-0.00382630379623308f, -0.028713422052654f, 0.0516362473449566f,
                                 0.0263641606741698f, -0.0187603084619177f, 0.0618569567549652f,
                                 0.00382630379623308f, 0.028713422052654f, -0.0516362473449566f,
                                -0.0263641606741698f, 0.0187603084619177f, -0.0618569567549652f};
        const float ly = -0.01f;
        const int jc[4]   = {0, 3, 6, 9};     // jpos cols per body {4,5,9,10}
        const int oc[4]   = {12, 21, 30, 39}; // ori  cols per body
        const int sbeg[4] = {0, 4, 6, 10};
        const int scnt[4] = {4, 2, 4, 2};
        #pragma unroll
        for (int bi = 0; bi < 4; ++bi) {
            const float jx = own[jc[bi]+0], jy = own[jc[bi]+1], jz = own[jc[bi]+2];
            const float* m = own + oc[bi];
            const float m00=m[0],m01=m[1],m02=m[2];
            const float m10=m[3],m11=m[4],m12=m[5];
            const float m20=m[6],m21=m[7],m22=m[8];
            const float kx = prv[jc[bi]+0], ky = prv[jc[bi]+1], kz = prv[jc[bi]+2];
            const float* nn = prv + oc[bi];
            const float n00=nn[0],n01=nn[1],n02=nn[2];
            const float n10=nn[3],n11=nn[4],n12=nn[5];
            const float n20=nn[6],n21=nn[7],n22=nn[8];
            #pragma unroll
            for (int si = 0; si < 4; ++si) {
                if (si < scnt[bi]) {
                    const int s = sbeg[bi] + si;
                    const float lx = c_lx[s], lz = c_lz[s];
                    const float ax = jx + m00*lx + m01*ly + m02*lz;
                    const float ay = jy + m10*lx + m11*ly + m12*lz;
                    const float az = jz + m20*lx + m21*ly + m22*lz;
                    const float bx = kx + n00*lx + n01*ly + n02*lz;
                    const float by = ky + n10*lx + n11*ly + n12*lz;
                    const float bz = kz + n20*lx + n21*ly + n22*lz;
                    px[s] = ax; py[s] = ay; pz[s] = az;
                    fx[s] = (ax - bx) * 20.0f;   // 1/DT = 20
                    fy[s] = (ay - by) * 20.0f;
                    fz[s] = (az - bz) * 20.0f;
                }
            }
        }
    }

    // ---- contact forces (round-1 numerics, in-place over velocity) ----
    const float KF  = 1077.21734501594f;                 // 0.5 * 100000**(2/3)
    const float CFH = (4.0f/3.0f) * KF * sqrtf(0.032f * KF);
    #pragma unroll
    for (int s = 0; s < 12; ++s) {
        const float vx = fx[s], vy = fy[s], vz = fz[s];
        const float ind     = -py[s];                    // GROUND_HEIGHT = 0
        const float ind_vel = -vy;
        const float q   = ind*ind + 1e-5f;
        const float fH  = CFH * sqrtf(q * sqrtf(q));     // q^0.75
        const float fHd = fH * (1.0f + 0.3f * ind_vel);  // 1.5*DISSIPATION = 0.3
        const float t1 = (0.5f*tanhf(50.0f*(ind_vel + 3.3333333333333335f)) + 0.5f) + 1e-16f;
        const float t2 = (0.5f*tanhf(300.0f*ind) + 0.5f) + 1e-16f;
        const float fn = t1 * t2 * fHd;
        const float vslip = sqrtf(vx*vx + vz*vz + 1e-5f);
        const float vrel  = vslip * 5.0f;                // / TRANSITION_VELOCITY
        // STATIC==DYNAMIC==0.8 -> 2*(S-D)/(1+vrel^2) term is exactly 0
        const float mu  = fminf(vrel, 1.0f) * 0.8f + 0.5f * vslip;
        const float ffr = fn * mu;
        const float sc  = ffr / (vslip + 1e-5f);
        fx[s] = -sc * vx;
        fy[s] = fn;
        fz[s] = -sc * vz;
    }

    // ---- group reductions: g=0 all, g=1 right(0..6), g=2 left(6..12) ----
    float res[3][9];
    const int gs0[3] = {0, 0, 6};
    const int gs1[3] = {12, 6, 12};
    #pragma unroll
    for (int g = 0; g < 3; ++g) {
        float Fx=0.f, Fy=0.f, Fz=0.f, tw=0.f, sx=0.f, sz=0.f;
        #pragma unroll
        for (int s = 0; s < 12; ++s) {
            if (s >= gs0[g] && s < gs1[g]) {
                Fx += fx[s]; Fy += fy[s]; Fz += fz[s];
                const float w = fy[s] > 0.f ? fy[s] : 0.f;
                tw += w;
                sx += px[s] * w;
                sz += pz[s] * w;
            }
        }
        const bool has = tw > 0.f;
        const float cx = has ? sx / tw : 0.f;
        const float cz = has ? sz / tw : 0.f;
        float Tx=0.f, Ty=0.f, Tz=0.f;
        #pragma unroll
        for (int s = 0; s < 12; ++s) {
            if (s >= gs0[g] && s < gs1[g]) {
                if (fy[s] > 0.f) {
                    const float rx = px[s]-cx, ry = py[s], rz = pz[s]-cz;  // cy==0
                    Tx += ry*fz[s] - rz*fy[s];
                    Ty += rz*fx[s] - rx*fz[s];
                    Tz += rx*fy[s] - ry*fx[s];
                }
            }
        }
        res[g][0]=Fx; res[g][1]=Fy; res[g][2]=Fz;
        res[g][3]=Tx; res[g][4]=Ty; res[g][5]=Tz;
        res[g][6]=cx; res[g][7]=0.f; res[g][8]=cz;
    }

    // ---- stores ----
    {
        const size_t sB = (size_t)B;
        const size_t t3 = (size_t)b * 3;
        float* o;
        o = out;           o[t3]=res[0][0]; o[t3+1]=res[0][1]; o[t3+2]=res[0][2];
        o = out + sB*3;    o[t3]=res[0][3]; o[t3+1]=res[0][4]; o[t3+2]=res[0][5];
        o = out + sB*6;    o[t3]=res[0][6]; o[t3+1]=res[0][7]; o[t3+2]=res[0][8];
        o = out + sB*81;   o[t3]=res[1][0]; o[t3+1]=res[1][1]; o[t3+2]=res[1][2];
        o = out + sB*84;   o[t3]=res[2][0]; o[t3+1]=res[2][1]; o[t3+2]=res[2][2];
        o = out + sB*87;   o[t3]=res[1][3]; o[t3+1]=res[1][4]; o[t3+2]=res[1][5];
        o = out + sB*90;   o[t3]=res[2][3]; o[t3+1]=res[2][4]; o[t3+2]=res[2][5];
        o = out + sB*93;   o[t3]=res[1][6]; o[t3+1]=res[1][7]; o[t3+2]=res[1][8];
        o = out + sB*96;   o[t3]=res[2][6]; o[t3+1]=res[2][7]; o[t3+2]=res[2][8];

        float* osf = out + sB*9  + (size_t)b*36;
        float* opp = out + sB*45 + (size_t)b*36;
        if ((B & 3) == 0) {   // 16B alignment of both region bases and b*144
            float bufF[36], bufP[36];
            #pragma unroll
            for (int s = 0; s < 12; ++s) {
                bufF[s*3+0]=fx[s]; bufF[s*3+1]=fy[s]; bufF[s*3+2]=fz[s];
                bufP[s*3+0]=px[s]; bufP[s*3+1]=py[s]; bufP[s*3+2]=pz[s];
            }
            #pragma unroll
            for (int i = 0; i < 9; ++i) {
                reinterpret_cast<float4*>(osf)[i] = reinterpret_cast<float4*>(bufF)[i];
                reinterpret_cast<float4*>(opp)[i] = reinterpret_cast<float4*>(bufP)[i];
            }
        } else {
            #pragma unroll
            for (int s = 0; s < 12; ++s) {
                osf[s*3+0]=fx[s]; osf[s*3+1]=fy[s]; osf[s*3+2]=fz[s];
                opp[s*3+0]=px[s]; opp[s*3+1]=py[s]; opp[s*3+2]=pz[s];
            }
        }
    }
}

extern "C" void kernel_launch(void* const* d_in, const int* in_sizes, int n_in,
                              void* d_out, int out_size, void* d_ws, size_t ws_size,
                              hipStream_t stream) {
    const float* joints = (const float*)d_in[0];
    const float* jori   = (const float*)d_in[1];
    float* out = (float*)d_out;
    const int B = in_sizes[0] / 72;        // joints is (B, 24, 3)
    int blocks = (B + 255) / 256;
    if (blocks < 1) blocks = 1;
    contact_kernel<<<blocks, 256, 0, stream>>>(joints, jori, out, B);
}